// Round 3
// baseline (218.868 us; speedup 1.0000x reference)
//
#include <hip/hip_runtime.h>
#include <stdint.h>

// Problem constants (fixed by the reference setup_inputs)
#define BATCH 128
#define SEQN  384                         // a rows (DP rows i)
#define SEQM  384                         // b rows (DP columns j)
#define DIM   128
#define KINF   1000000.0f                 // reference pseudo-infinity (nat units)
#define LOG2E  1.4426950408889634f
#define LN2    0.6931471805599453f
#define KINF2  (KINF * LOG2E)             // pseudo-infinity in base-2-scaled units
#define NCOLS  388                        // 384 D-cols + 4 baked-KINF2 pad cols

// Consumer split geometry: 2 DP waves x 64 lanes x 3 rows
#define OFF1   162                        // wave1 column offset: 128 + 2*SLACK
#define SLACK  17                         // boundary ring read lag (PHASE2 units)
#define RBMASK 63                         // 64-entry boundary ring

// hardware base-2 transcendentals (v_exp_f32 / v_log_f32)
#define EXP2F(x) __builtin_amdgcn_exp2f(x)
#define LOG2F(x) __builtin_amdgcn_logf(x)

#define WG __HIP_MEMORY_SCOPE_WORKGROUP

typedef __attribute__((ext_vector_type(8))) short bf16x8;   // 8 bf16 = 4 VGPRs (MFMA A/B frag)
typedef __attribute__((ext_vector_type(4))) float f32x4;    // MFMA C/D frag

__device__ __forceinline__ unsigned short bf16_rne(float x) {
    uint32_t u = __float_as_uint(x);
    u += 0x7FFFu + ((u >> 16) & 1u);
    return (unsigned short)(u >> 16);
}
__device__ __forceinline__ uint32_t bf16_pair(float x, float y) {
    uint32_t ux = __float_as_uint(x); ux += 0x7FFFu + ((ux >> 16) & 1u);
    uint32_t uy = __float_as_uint(y); uy += 0x7FFFu + ((uy >> 16) & 1u);
    return (ux >> 16) | (uy & 0xFFFF0000u);
}

union frag_u { bf16x8 v; uint32_t u[4]; };
struct us3 { unsigned short u[3]; };

#define SPIN_NZ(addr)                                                        \
    { int g_ = 0;                                                            \
      while (__hip_atomic_load((addr), __ATOMIC_ACQUIRE, WG) == 0)           \
          if (++g_ > (1 << 20)) break; }
#define SPIN_GE(addr, val)                                                   \
    { int g_ = 0;                                                            \
      while (__hip_atomic_load((addr), __ATOMIC_ACQUIRE, WG) < (val))        \
          if (++g_ > (1 << 20)) break; }

// ---------------------------------------------------------------------------
// Fused kernel, one block per batch, 5 waves (320 thr), 1 block/CU:
//   waves 0,1 : soft-DTW DP split by rows (0..191 / 192..383, 3 rows/lane).
//               Identical per-cell math to the passing kernel; wave0's
//               bottom-row values flow to wave1 via a 64-entry LDS ring
//               with SLACK=17 PHASE2s of lag (progress counters each way).
//   waves 2-4 : producers. Stage A once into LDS (bf16, swizzled) + normA,
//               then chunk k (32 D-cols) = B-frags from global + 24 MFMA
//               row-groups, written to GLOBAL D (round-0 layout). No ring
//               capacity limit -> producers free-run; consumers gate on
//               prod_done[k] only.
// ---------------------------------------------------------------------------
__global__ __launch_bounds__(320) void fused_dtw(
        const float* __restrict__ A, const float* __restrict__ B,
        unsigned short* __restrict__ Dt, float* __restrict__ out) {
    __shared__ __align__(16) unsigned short ldsA[SEQN][DIM];   // 98,304 B
    __shared__ __align__(16) float normA[SEQN];                //  1,536 B
    __shared__ __align__(8)  float bring[128];                 //    512 B (64 x 2)
    __shared__ int prod_done[16];
    __shared__ int w0_prog, w1_prog, stage_cnt;

    const int bat  = blockIdx.x;
    const int tid  = threadIdx.x;
    const int wv   = tid >> 6;
    const int lane = tid & 63;

    if (tid < 16) prod_done[tid] = 0;
    if (tid == 16) w0_prog = -1;
    if (tid == 17) w1_prog = -1;
    if (tid == 18) stage_cnt = 0;
    __syncthreads();                       // only block-wide sync in the kernel

    unsigned short* __restrict__ DtB = Dt + (long)bat * NCOLS * SEQN;

    if (wv >= 2) {
        // ========================= PRODUCERS (waves 2..4) ====================
        const int pt = tid - 128;          // 0..191
        const float* __restrict__ Ab = A + (long)bat * SEQN * DIM;
        const float* __restrict__ Bb = B + (long)bat * SEQM * DIM;

        // ---- stage A -> ldsA (bf16, swizzled) + normA; 32 passes, 4-batched ----
        for (int sp = 0; sp < 8; sp++) {
            float4 v0[4], v1[4];
            #pragma unroll
            for (int j = 0; j < 4; j++) {
                int e = (sp * 4 + j) * 1536 + pt * 8;
                v0[j] = *(const float4*)(Ab + e);
                v1[j] = *(const float4*)(Ab + e + 4);
            }
            #pragma unroll
            for (int j = 0; j < 4; j++) {
                int e   = (sp * 4 + j) * 1536 + pt * 8;
                int row = e >> 7;
                int grp = (e >> 3) & 15;
                int sw  = (grp ^ (row & 15)) * 8;
                uint4 va;
                va.x = bf16_pair(v0[j].x, v0[j].y); va.y = bf16_pair(v0[j].z, v0[j].w);
                va.z = bf16_pair(v1[j].x, v1[j].y); va.w = bf16_pair(v1[j].z, v1[j].w);
                *(uint4*)&ldsA[row][sw] = va;
                float sa = v0[j].x*v0[j].x + v0[j].y*v0[j].y + v0[j].z*v0[j].z + v0[j].w*v0[j].w
                         + v1[j].x*v1[j].x + v1[j].y*v1[j].y + v1[j].z*v1[j].z + v1[j].w*v1[j].w;
                #pragma unroll
                for (int off = 8; off > 0; off >>= 1) sa += __shfl_down(sa, off, 16);
                if ((pt & 15) == 0) normA[row] = sa;
            }
        }
        // producer-only barrier (consumers don't touch ldsA/normA)
        if (lane == 0) __hip_atomic_fetch_add(&stage_cnt, 1, __ATOMIC_RELEASE, WG);
        SPIN_GE(&stage_cnt, 3);

        const int l16 = lane & 15, q = lane >> 4;
        for (int k = wv - 2; k < 13; k += 3) {
            if (k == 12) {
                // pad cols 384..387 = KINF2 (INF-flow right edge)
                uint32_t pv = bf16_pair(KINF2, KINF2);
                #pragma unroll
                for (int c = 0; c < 4; c++) {
                    uint32_t* p = (uint32_t*)(DtB + (long)(384 + c) * SEQN + 6 * lane);
                    p[0] = pv; p[1] = pv; p[2] = pv;
                }
            } else {
                // B fragments for 32 cols (2 j-groups of 16) + b-norms
                frag_u bfrag[2][4];
                float bn[2];
                #pragma unroll
                for (int jg = 0; jg < 2; jg++) {
                    const float* bp = Bb + (long)(32 * k + jg * 16 + l16) * DIM + q * 8;
                    float s = 0.0f;
                    #pragma unroll
                    for (int kk = 0; kk < 4; kk++) {
                        float4 w0 = *(const float4*)(bp + kk * 32);
                        float4 w1 = *(const float4*)(bp + kk * 32 + 4);
                        bfrag[jg][kk].u[0] = bf16_pair(w0.x, w0.y);
                        bfrag[jg][kk].u[1] = bf16_pair(w0.z, w0.w);
                        bfrag[jg][kk].u[2] = bf16_pair(w1.x, w1.y);
                        bfrag[jg][kk].u[3] = bf16_pair(w1.z, w1.w);
                        s += w0.x*w0.x + w0.y*w0.y + w0.z*w0.z + w0.w*w0.w
                           + w1.x*w1.x + w1.y*w1.y + w1.z*w1.z + w1.w*w1.w;
                    }
                    s += __shfl_xor(s, 16, 64);
                    s += __shfl_xor(s, 32, 64);
                    bn[jg] = s;
                }
                // 24 A row-groups from LDS (staged once)
                for (int si = 0; si < 24; si++) {
                    const int arow = si * 16 + l16;
                    frag_u afr[4];
                    #pragma unroll
                    for (int kk = 0; kk < 4; kk++)
                        afr[kk].v = *(const bf16x8*)&ldsA[arow][((kk * 4 + q) ^ (arow & 15)) * 8];
                    f32x4 acc0 = {0.0f, 0.0f, 0.0f, 0.0f};
                    f32x4 acc1 = {0.0f, 0.0f, 0.0f, 0.0f};
                    #pragma unroll
                    for (int kk = 0; kk < 4; kk++) {
                        acc0 = __builtin_amdgcn_mfma_f32_16x16x32_bf16(
                                   afr[kk].v, bfrag[0][kk].v, acc0, 0, 0, 0);
                        acc1 = __builtin_amdgcn_mfma_f32_16x16x32_bf16(
                                   afr[kk].v, bfrag[1][kk].v, acc1, 0, 0, 0);
                    }
                    float4 an = *(const float4*)&normA[si * 16 + q * 4];
                    #pragma unroll
                    for (int jg = 0; jg < 2; jg++) {
                        int col = 32 * k + jg * 16 + l16;
                        f32x4 ac = jg ? acc1 : acc0;
                        ushort4 pk;
                        pk.x = bf16_rne((an.x + bn[jg] - 2.0f * ac[0]) * LOG2E);
                        pk.y = bf16_rne((an.y + bn[jg] - 2.0f * ac[1]) * LOG2E);
                        pk.z = bf16_rne((an.z + bn[jg] - 2.0f * ac[2]) * LOG2E);
                        pk.w = bf16_rne((an.w + bn[jg] - 2.0f * ac[3]) * LOG2E);
                        *(ushort4*)(DtB + (long)col * SEQN + si * 16 + q * 4) = pk;
                    }
                }
            }
            if (lane == 0)
                __hip_atomic_store(&prod_done[k], 1, __ATOMIC_RELEASE, WG);
        }
        return;
    }

    // ===================== CONSUMERS (waves 0,1): soft-DTW DP ================
    const int  cw    = wv;                 // 0: rows 0..191, 1: rows 192..383
    const int  t     = lane;
    const bool isl0  = (t == 0);
    const int  off   = cw ? OFF1 : 0;
    const int  npair = cw ? 168 : 160;     // PHASE2 count = 2*npair
    const unsigned short* __restrict__ dtb = DtB + 192 * cw + 3 * t;

    SPIN_NZ(&prod_done[0]);

    float prev[3];
    #pragma unroll
    for (int r = 0; r < 3; r++) prev[r] = KINF2;

    us3 dslot[4];                          // slot qq holds D column (c0 + qq)
    #pragma unroll
    for (int qq = 0; qq < 4; qq++) {
        int c = qq - 2 * t - off;
        int cc = c < 0 ? 0 : c;
        long base = (long)cc * SEQN;
        dslot[qq].u[0] = dtb[base];
        dslot[qq].u[1] = dtb[base + 1];
        dslot[qq].u[2] = dtb[base + 2];
    }

    float rcv0 = KINF2, rcv1 = KINF2, old_diag = KINF2;
    float lane0_diag = cw ? KINF2 : 0.0f;  // R[0][0] seed lives in wave0 only
    float b_rcv0 = KINF2, b_rcv1 = KINF2, b_old = KINF2;   // wave1 boundary regs
    float botA = KINF2, botB = KINF2;
    int c0 = -2 * t - off;
    int kdone = 0;

#define UNPACK3(d, w)                                                       \
    d[0] = __uint_as_float(((uint32_t)w.u[0]) << 16);                       \
    d[1] = __uint_as_float(((uint32_t)w.u[1]) << 16);                       \
    d[2] = __uint_as_float(((uint32_t)w.u[2]) << 16);

#define COLPASS(dX, diag0, upseed, LEFTV, NEWV)                             \
    {                                                                       \
        float Bp = (upseed), Fp = 1.0f;                                     \
        float Bv[3], Fv[3];                                                 \
        _Pragma("unroll")                                                   \
        for (int r = 0; r < 3; r++) {                                       \
            float vd = (r == 0) ? (diag0) : LEFTV[r - 1];                   \
            float vl = LEFTV[r];                                            \
            float m3 = fminf(fminf(vd, vl), Bp);     /* v_min3_f32 */       \
            float al = EXP2F(m3 - Bp);                                      \
            float be = EXP2F(m3 - vd) + EXP2F(m3 - vl);                     \
            float Fr = __builtin_fmaf(al, Fp, be);                          \
            float Br = dX[r] + m3;                                          \
            Bv[r] = Br; Fv[r] = Fr;                                         \
            Bp = Br; Fp = Fr;                                               \
        }                                                                   \
        _Pragma("unroll")                                                   \
        for (int r = 0; r < 3; r++)                                         \
            NEWV[r] = Bv[r] - LOG2F(Fv[r]);                                 \
    }

#define PHASE2(Q)                                                           \
    {                                                                       \
        us3 wA = dslot[Q];                                                  \
        us3 wB = dslot[(Q) + 1];                                            \
        {   /* refill both slots for phase p+2 from global D */             \
            int cnA = c0 + 4;                                               \
            int ccA = cnA < 0 ? 0 : (cnA > 387 ? 387 : cnA);                \
            int cnB = c0 + 5;                                               \
            int ccB = cnB < 0 ? 0 : (cnB > 387 ? 387 : cnB);                \
            long bA = (long)ccA * SEQN;                                     \
            long bB = (long)ccB * SEQN;                                     \
            dslot[Q].u[0]       = dtb[bA];                                  \
            dslot[Q].u[1]       = dtb[bA + 1];                              \
            dslot[Q].u[2]       = dtb[bA + 2];                              \
            dslot[(Q) + 1].u[0] = dtb[bB];                                  \
            dslot[(Q) + 1].u[1] = dtb[bB + 1];                              \
            dslot[(Q) + 1].u[2] = dtb[bB + 2];                              \
        }                                                                   \
        float dA[3], dB[3];                                                 \
        UNPACK3(dA, wA)                                                     \
        UNPACK3(dB, wB)                                                     \
        float dgA = isl0 ? (cw ? b_old  : lane0_diag) : old_diag;           \
        float upA = isl0 ? (cw ? b_rcv0 : KINF2)      : rcv0;               \
        float upB = isl0 ? (cw ? b_rcv1 : KINF2)      : rcv1;               \
        float newA[3];                                                      \
        COLPASS(dA, dgA, upA, prev, newA)                                   \
        COLPASS(dB, upA, upB, newA, prev)                                   \
        old_diag = rcv1;                                                    \
        rcv0 = __shfl_up(newA[2], 1, 64);                                   \
        rcv1 = __shfl_up(prev[2], 1, 64);                                   \
        botA = newA[2]; botB = prev[2];                                     \
        lane0_diag = KINF2;                                                 \
        c0 += 2;                                                            \
    }

    // TAILs: boundary ring traffic after each PHASE2 (m/n = PHASE2 index)
#define TAIL0(m)                                                            \
    {                                                                       \
        if (t == 63) {                                                      \
            *(float2*)&bring[((m) & RBMASK) * 2] = make_float2(botA, botB); \
            if (((m) & 7) == 7)                                             \
                __hip_atomic_store(&w0_prog, (m), __ATOMIC_RELEASE, WG);    \
        }                                                                   \
    }
#define TAIL1(n)                                                            \
    {                                                                       \
        b_old = b_rcv1;                                                     \
        if ((n) >= SLACK) {                                                 \
            float2 bv = *(float2*)&bring[(((n) - SLACK) & RBMASK) * 2];     \
            b_rcv0 = bv.x; b_rcv1 = bv.y;                                   \
        } else { b_rcv0 = KINF2; b_rcv1 = KINF2; }                          \
        if (((n) & 7) == 7 && t == 63)                                      \
            __hip_atomic_store(&w1_prog, (n), __ATOMIC_RELEASE, WG);        \
    }

    for (int p = 0; p < npair; p++) {
        if ((p & 3) == 3) {
            // chunk gate: refills of PHASE2s 2p..2p+7 touch cols <= 4p+19-off
            int kr = (4 * p + 19 - off) >> 5;
            if (kr > 12) kr = 12;
            if (kr > kdone) { SPIN_NZ(&prod_done[kr]); kdone = kr; }
            if (cw) {        // availability: slots read through 2p-10
                int thr = 2 * p - 10;
                if (thr > 318) thr = 318;  // wave0 stops publishing at 319
                if (thr >= 0) SPIN_GE(&w0_prog, thr);
            } else {         // overwrite guard: wave1 must have read slot 2p-57
                int thr = 2 * p - 40;
                if (thr >= 0) SPIN_GE(&w1_prog, thr);
            }
        }
        PHASE2(0)
        if (cw == 0) TAIL0(2 * p) else TAIL1(2 * p)
        PHASE2(2)
        if (cw == 0) TAIL0(2 * p + 1) else TAIL1(2 * p + 1)
    }
#undef PHASE2
#undef COLPASS
#undef UNPACK3
#undef TAIL0
#undef TAIL1

    // wave1 lane63, last PHASE2 colB = D-col 383 (DP j=384): prev[2] = R[384][384]
    if (cw == 1 && t == 63) out[bat] = prev[2] * LN2;
}

// ---------------------------------------------------------------------------
extern "C" void kernel_launch(void* const* d_in, const int* in_sizes, int n_in,
                              void* d_out, int out_size, void* d_ws, size_t ws_size,
                              hipStream_t stream) {
    (void)in_sizes; (void)n_in; (void)out_size; (void)ws_size;
    const float* a = (const float*)d_in[0];
    const float* b = (const float*)d_in[1];
    float* out = (float*)d_out;

    // ws layout: Dt only (388 cols x 384 rows x 128 batches, bf16) = 38.1 MB
    unsigned short* Dmat = (unsigned short*)d_ws;

    fused_dtw<<<dim3(BATCH), dim3(320), 0, stream>>>(a, b, Dmat, out);
}